// Round 1
// baseline (1679.691 us; speedup 1.0000x reference)
//
#include <hip/hip_runtime.h>

// SVF 3D scaling-and-squaring integrator.
// disp0 = v * 2^-32; 32x: disp = disp + trilinear(disp, id + disp); out = (id+disp, disp).
// Internal layout: AoS float4 per voxel (dx,dy,dz,pad) [N,D,H,W,4] so each gather
// corner's 3 channels live in one 16B chunk (1-2 cache lines vs 3 for planar).

#define NSTEPS 32

constexpr int Dd = 128, Hh = 128, Ww = 128, Nb = 2, Cc = 3;
constexpr int VOX = Dd * Hh * Ww;   // 2,097,152
constexpr int NV  = Nb * VOX;       // 4,194,304
constexpr int THREADS = 256;

__global__ __launch_bounds__(THREADS) void svf_init(const float* __restrict__ v,
                                                    float4* __restrict__ A) {
    int i = blockIdx.x * THREADS + threadIdx.x;       // 0..NV-1
    int n = i >> 21;                                   // i / VOX
    int s = i & (VOX - 1);
    const float sc = 2.3283064365386963e-10f;          // 2^-32 (exact)
    int b = n * Cc * VOX + s;
    float dx = v[b]           * sc;
    float dy = v[b + VOX]     * sc;
    float dz = v[b + 2 * VOX] * sc;
    A[i] = make_float4(dx, dy, dz, 0.0f);
}

__global__ __launch_bounds__(THREADS) void svf_step(const float4* __restrict__ src,
                                                    float4* __restrict__ dst,
                                                    const float* __restrict__ idg) {
    int i = blockIdx.x * THREADS + threadIdx.x;
    int s = i & (VOX - 1);
    int base = i - s;                                  // n*VOX

    float4 d = src[i];
    float id_x = idg[3 * s + 0];
    float id_y = idg[3 * s + 1];
    float id_z = idg[3 * s + 2];

    // reference: t = id + disp; i = clip((t + 1.0) * 0.5 * (dim-1), 0, dim-1)
    float ix = ((id_x + d.x) + 1.0f) * 0.5f * 127.0f;
    float iy = ((id_y + d.y) + 1.0f) * 0.5f * 127.0f;
    float iz = ((id_z + d.z) + 1.0f) * 0.5f * 127.0f;
    ix = fminf(fmaxf(ix, 0.0f), 127.0f);
    iy = fminf(fmaxf(iy, 0.0f), 127.0f);
    iz = fminf(fmaxf(iz, 0.0f), 127.0f);

    float x0f = floorf(ix), y0f = floorf(iy), z0f = floorf(iz);
    float fx = ix - x0f, fy = iy - y0f, fz = iz - z0f;
    int x0 = (int)x0f, y0 = (int)y0f, z0 = (int)z0f;
    int x1 = min(x0 + 1, 127);
    int y1 = min(y0 + 1, 127);
    int z1 = min(z0 + 1, 127);

    float wx0 = 1.0f - fx, wy0 = 1.0f - fy, wz0 = 1.0f - fz;

    // row offsets (z*H + y)*W
    int r00 = base + (z0 << 14) + (y0 << 7);
    int r01 = base + (z0 << 14) + (y1 << 7);
    int r10 = base + (z1 << 14) + (y0 << 7);
    int r11 = base + (z1 << 14) + (y1 << 7);

    float4 g000 = src[r00 + x0];
    float4 g001 = src[r00 + x1];
    float4 g010 = src[r01 + x0];
    float4 g011 = src[r01 + x1];
    float4 g100 = src[r10 + x0];
    float4 g101 = src[r10 + x1];
    float4 g110 = src[r11 + x0];
    float4 g111 = src[r11 + x1];

    // weights in the reference's grouping/order
    float w000 = wz0 * wy0 * wx0;
    float w001 = wz0 * wy0 * fx;
    float w010 = wz0 * fy  * wx0;
    float w011 = wz0 * fy  * fx;
    float w100 = fz  * wy0 * wx0;
    float w101 = fz  * wy0 * fx;
    float w110 = fz  * fy  * wx0;
    float w111 = fz  * fy  * fx;

    float ox = g000.x * w000 + g001.x * w001 + g010.x * w010 + g011.x * w011
             + g100.x * w100 + g101.x * w101 + g110.x * w110 + g111.x * w111;
    float oy = g000.y * w000 + g001.y * w001 + g010.y * w010 + g011.y * w011
             + g100.y * w100 + g101.y * w101 + g110.y * w110 + g111.y * w111;
    float oz = g000.z * w000 + g001.z * w001 + g010.z * w010 + g011.z * w011
             + g100.z * w100 + g101.z * w101 + g110.z * w110 + g111.z * w111;

    dst[i] = make_float4(d.x + ox, d.y + oy, d.z + oz, 0.0f);
}

__global__ __launch_bounds__(THREADS) void svf_final(const float4* __restrict__ A,
                                                     const float* __restrict__ idg,
                                                     float* __restrict__ out) {
    int i = blockIdx.x * THREADS + threadIdx.x;
    int n = i >> 21;
    int s = i & (VOX - 1);
    float4 d = A[i];
    float id_x = idg[3 * s + 0];
    float id_y = idg[3 * s + 1];
    float id_z = idg[3 * s + 2];

    int ob = n * Cc * VOX + s;
    // transformation = identity (planar) + displacement
    out[ob]            = id_x + d.x;
    out[ob + VOX]      = id_y + d.y;
    out[ob + 2 * VOX]  = id_z + d.z;
    // displacement
    float* disp_out = out + (size_t)Nb * Cc * VOX;
    disp_out[ob]           = d.x;
    disp_out[ob + VOX]     = d.y;
    disp_out[ob + 2 * VOX] = d.z;
}

extern "C" void kernel_launch(void* const* d_in, const int* in_sizes, int n_in,
                              void* d_out, int out_size, void* d_ws, size_t ws_size,
                              hipStream_t stream) {
    const float* v   = (const float*)d_in[0];
    const float* idg = (const float*)d_in[1];
    float* out = (float*)d_out;

    // Ping-pong buffers: A in workspace (NV*16 = 67.1 MB), B aliased onto d_out
    // (out buffer is 100.7 MB; fully rewritten by svf_final which reads only A).
    float4* A = (float4*)d_ws;
    float4* B = (float4*)d_out;

    dim3 grid(NV / THREADS), block(THREADS);

    svf_init<<<grid, block, 0, stream>>>(v, A);
    for (int k = 0; k < NSTEPS; ++k) {
        const float4* src = (k & 1) ? (const float4*)B : (const float4*)A;
        float4*       dst = (k & 1) ? A : B;
        svf_step<<<grid, block, 0, stream>>>(src, dst, idg);
    }
    // After an even number of steps the result is back in A.
    svf_final<<<grid, block, 0, stream>>>(A, idg, out);
}

// Round 2
// 1388.292 us; speedup vs baseline: 1.2099x; 1.2099x over previous
//
#include <hip/hip_runtime.h>

// SVF 3D scaling-and-squaring integrator, round 2.
// disp0 = v * 2^-32; 32x: disp = disp + trilinear(disp, id + disp); out = (id+disp, disp).
// AoS float4 per voxel. Changes vs round 1:
//  - identity grid replaced by three 128-entry tables (bit-exact, extracted from input)
//    -> kills ~25 MB/step idg stream (and its 8x XCD L2 duplication).
//  - XCD-chunked blockIdx swizzle in svf_step for L2 slab locality.

#define NSTEPS 32

constexpr int Dd = 128, Hh = 128, Ww = 128, Nb = 2, Cc = 3;
constexpr int VOX = Dd * Hh * Ww;   // 2,097,152
constexpr int NV  = Nb * VOX;       // 4,194,304
constexpr int THREADS = 256;
constexpr int NBLK = NV / THREADS;  // 16384
constexpr int NXCD = 8;

// [0..127]=x-table, [128..255]=y-table, [256..383]=z-table
__device__ float g_tab[3 * 128];

__global__ __launch_bounds__(128) void extract_tables(const float* __restrict__ idg) {
    int t = threadIdx.x;  // 128 threads
    // idg layout [D,H,W,3]: idx = ((z*128+y)*128+x)*3 + c
    g_tab[t]       = idg[3 * t];             // x varies, y=z=0, c=0
    g_tab[128 + t] = idg[3 * (t << 7) + 1];  // y varies, c=1
    g_tab[256 + t] = idg[3 * (t << 14) + 2]; // z varies, c=2
}

__global__ __launch_bounds__(THREADS) void svf_init(const float* __restrict__ v,
                                                    float4* __restrict__ A) {
    int i = blockIdx.x * THREADS + threadIdx.x;       // 0..NV-1
    int n = i >> 21;                                   // i / VOX
    int s = i & (VOX - 1);
    const float sc = 2.3283064365386963e-10f;          // 2^-32 (exact)
    int b = n * Cc * VOX + s;
    float dx = v[b]           * sc;
    float dy = v[b + VOX]     * sc;
    float dz = v[b + 2 * VOX] * sc;
    A[i] = make_float4(dx, dy, dz, 0.0f);
}

__global__ __launch_bounds__(THREADS) void svf_step(const float4* __restrict__ src,
                                                    float4* __restrict__ dst) {
    // XCD-chunked bijective swizzle: NBLK % 8 == 0, each XCD gets a contiguous slab.
    int bid = blockIdx.x;
    int swz = (bid & (NXCD - 1)) * (NBLK / NXCD) + (bid >> 3);
    int i = swz * THREADS + threadIdx.x;
    int s = i & (VOX - 1);
    int base = i - s;                                  // n*VOX

    int xg = s & 127;
    int yg = (s >> 7) & 127;
    int zg = s >> 14;

    float4 d = src[i];
    float id_x = g_tab[xg];
    float id_y = g_tab[128 + yg];
    float id_z = g_tab[256 + zg];

    // reference: t = id + disp; i = clip((t + 1.0) * 0.5 * (dim-1), 0, dim-1)
    float ix = ((id_x + d.x) + 1.0f) * 0.5f * 127.0f;
    float iy = ((id_y + d.y) + 1.0f) * 0.5f * 127.0f;
    float iz = ((id_z + d.z) + 1.0f) * 0.5f * 127.0f;
    ix = fminf(fmaxf(ix, 0.0f), 127.0f);
    iy = fminf(fmaxf(iy, 0.0f), 127.0f);
    iz = fminf(fmaxf(iz, 0.0f), 127.0f);

    float x0f = floorf(ix), y0f = floorf(iy), z0f = floorf(iz);
    float fx = ix - x0f, fy = iy - y0f, fz = iz - z0f;
    int x0 = (int)x0f, y0 = (int)y0f, z0 = (int)z0f;
    int x1 = min(x0 + 1, 127);
    int y1 = min(y0 + 1, 127);
    int z1 = min(z0 + 1, 127);

    float wx0 = 1.0f - fx, wy0 = 1.0f - fy, wz0 = 1.0f - fz;

    int r00 = base + (z0 << 14) + (y0 << 7);
    int r01 = base + (z0 << 14) + (y1 << 7);
    int r10 = base + (z1 << 14) + (y0 << 7);
    int r11 = base + (z1 << 14) + (y1 << 7);

    float4 g000 = src[r00 + x0];
    float4 g001 = src[r00 + x1];
    float4 g010 = src[r01 + x0];
    float4 g011 = src[r01 + x1];
    float4 g100 = src[r10 + x0];
    float4 g101 = src[r10 + x1];
    float4 g110 = src[r11 + x0];
    float4 g111 = src[r11 + x1];

    float w000 = wz0 * wy0 * wx0;
    float w001 = wz0 * wy0 * fx;
    float w010 = wz0 * fy  * wx0;
    float w011 = wz0 * fy  * fx;
    float w100 = fz  * wy0 * wx0;
    float w101 = fz  * wy0 * fx;
    float w110 = fz  * fy  * wx0;
    float w111 = fz  * fy  * fx;

    float ox = g000.x * w000 + g001.x * w001 + g010.x * w010 + g011.x * w011
             + g100.x * w100 + g101.x * w101 + g110.x * w110 + g111.x * w111;
    float oy = g000.y * w000 + g001.y * w001 + g010.y * w010 + g011.y * w011
             + g100.y * w100 + g101.y * w101 + g110.y * w110 + g111.y * w111;
    float oz = g000.z * w000 + g001.z * w001 + g010.z * w010 + g011.z * w011
             + g100.z * w100 + g101.z * w101 + g110.z * w110 + g111.z * w111;

    dst[i] = make_float4(d.x + ox, d.y + oy, d.z + oz, 0.0f);
}

__global__ __launch_bounds__(THREADS) void svf_final(const float4* __restrict__ A,
                                                     float* __restrict__ out) {
    int i = blockIdx.x * THREADS + threadIdx.x;
    int n = i >> 21;
    int s = i & (VOX - 1);

    int xg = s & 127;
    int yg = (s >> 7) & 127;
    int zg = s >> 14;

    float4 d = A[i];
    float id_x = g_tab[xg];
    float id_y = g_tab[128 + yg];
    float id_z = g_tab[256 + zg];

    int ob = n * Cc * VOX + s;
    out[ob]            = id_x + d.x;
    out[ob + VOX]      = id_y + d.y;
    out[ob + 2 * VOX]  = id_z + d.z;
    float* disp_out = out + (size_t)Nb * Cc * VOX;
    disp_out[ob]           = d.x;
    disp_out[ob + VOX]     = d.y;
    disp_out[ob + 2 * VOX] = d.z;
}

extern "C" void kernel_launch(void* const* d_in, const int* in_sizes, int n_in,
                              void* d_out, int out_size, void* d_ws, size_t ws_size,
                              hipStream_t stream) {
    const float* v   = (const float*)d_in[0];
    const float* idg = (const float*)d_in[1];
    float* out = (float*)d_out;

    // Ping-pong: A in workspace (67.1 MB), B aliased onto d_out (fully rewritten
    // by svf_final, which reads only A; 32 steps is even so chain ends in A).
    float4* A = (float4*)d_ws;
    float4* B = (float4*)d_out;

    dim3 grid(NBLK), block(THREADS);

    extract_tables<<<1, 128, 0, stream>>>(idg);
    svf_init<<<grid, block, 0, stream>>>(v, A);
    for (int k = 0; k < NSTEPS; ++k) {
        const float4* src = (k & 1) ? (const float4*)B : (const float4*)A;
        float4*       dst = (k & 1) ? A : B;
        svf_step<<<grid, block, 0, stream>>>(src, dst);
    }
    svf_final<<<grid, block, 0, stream>>>(A, out);
}